// Round 1
// baseline (412.045 us; speedup 1.0000x reference)
//
#include <hip/hip_runtime.h>
#include <hip/hip_bf16.h>

// Problem constants (fixed by reference setup_inputs)
constexpr int Bb   = 2;
constexpr int Tt   = 4;
constexpr int Himg = 256;
constexpr int Wimg = 256;
constexpr int SP   = 64;
constexpr int NH   = 7;      // (256-64)/32+1
constexpr int NWIN = 49;     // NH*NH
constexpr int CENC = 512;
constexpr int Dd   = 128;

// workspace layout (floats)
constexpr int OFF_WS   = 0;                  // [B][T][SP][NWIN] = 25088
constexpr int OFF_CNT  = 25088;              // [B][T][SP]       = 512
constexpr int OFF_Q    = 25600;              // [B][D][T][NWIN]  = 50176
constexpr int OFF_QSP  = 75776;              // [B][D][T][SP]    = 65536
constexpr int OFF_A12  = 141312;             // [B][3][SP][SP]   = 24576
constexpr int OFF_A21  = 165888;             // [B][3][SP][SP]   = 24576

// ---------------------------------------------------------------------------
// K1: scatter sp_mask -> window sums (ws[b,t,s,win] = sum over window pixels
// with label s of 1/sm) and per-label pixel counts.
// grid = B*T*8 (8 row-bands of 32 rows), block = 256
__global__ void k_scatter(const int* __restrict__ mask,
                          float* __restrict__ ws, float* __restrict__ cnt) {
    int blk = blockIdx.x;
    int rb  = blk & 7;        // row band: rows [32*rb, 32*rb+31]
    int bt  = blk >> 3;       // b*T + t
    __shared__ float loc[2 * NH * SP];   // [wy-slot][wx][s]
    __shared__ float lcnt[SP];
    for (int i = threadIdx.x; i < 2 * NH * SP; i += 256) loc[i] = 0.f;
    if (threadIdx.x < SP) lcnt[threadIdx.x] = 0.f;
    __syncthreads();

    int x = threadIdx.x;          // column
    int cx = x >> 5;
    int wx0 = cx - 1, wx1 = cx;
    bool wx0v = (wx0 >= 0), wx1v = (wx1 <= 6);
    float cw = ((x < 32) || (x >= 224)) ? 1.f : 2.f;
    bool s0v = (rb - 1 >= 0);     // wy = rb-1 slot
    bool s1v = (rb <= 6);         // wy = rb   slot
    const int* mrow = mask + bt * (Himg * Wimg) + (rb * 32) * Wimg;

    for (int k = 0; k < 32; ++k) {
        int y = rb * 32 + k;
        int s = mrow[k * Wimg + x];
        float rw = ((y < 32) || (y >= 224)) ? 1.f : 2.f;
        float w = 1.f / (rw * cw);
        atomicAdd(&lcnt[s], 1.f);
        if (s0v) {
            if (wx0v) atomicAdd(&loc[0 * NH * SP + wx0 * SP + s], w);
            if (wx1v) atomicAdd(&loc[0 * NH * SP + wx1 * SP + s], w);
        }
        if (s1v) {
            if (wx0v) atomicAdd(&loc[1 * NH * SP + wx0 * SP + s], w);
            if (wx1v) atomicAdd(&loc[1 * NH * SP + wx1 * SP + s], w);
        }
    }
    __syncthreads();
    for (int i = threadIdx.x; i < 2 * NH * SP; i += 256) {
        int slot = i / (NH * SP);
        int wx   = (i / SP) % NH;
        int s    = i & 63;
        bool valid = slot == 0 ? s0v : s1v;
        if (valid) {
            float v = loc[i];
            if (v != 0.f) {
                int wy = rb - 1 + slot;
                atomicAdd(&ws[(bt * SP + s) * NWIN + wy * NH + wx], v);
            }
        }
    }
    if (threadIdx.x < SP)
        atomicAdd(&cnt[bt * SP + threadIdx.x], lcnt[threadIdx.x]);
}

// ---------------------------------------------------------------------------
// K2: q[b,d,t,n] = normalize_d( sum_c feats[b,n,c,t] * W_head[c,d] )
// grid = B*NWIN = 98, block = 128 (one thread per d, all 4 t per thread)
__global__ void k_q(const float* __restrict__ feats, const float* __restrict__ Wh,
                    float* __restrict__ q) {
    int blk = blockIdx.x;
    int n = blk % NWIN, b = blk / NWIN;
    __shared__ float f[CENC * Tt];   // [c][t]
    __shared__ float wsum[2];
    const float* fp = feats + (size_t)(b * NWIN + n) * CENC * Tt;
    for (int i = threadIdx.x; i < CENC * Tt; i += 128) f[i] = fp[i];
    __syncthreads();

    int d = threadIdx.x;
    float acc[Tt] = {0.f, 0.f, 0.f, 0.f};
    for (int c = 0; c < CENC; ++c) {
        float w = Wh[c * Dd + d];
        acc[0] += f[c * 4 + 0] * w;
        acc[1] += f[c * 4 + 1] * w;
        acc[2] += f[c * 4 + 2] * w;
        acc[3] += f[c * 4 + 3] * w;
    }
    for (int t = 0; t < Tt; ++t) {
        float ss = acc[t] * acc[t];
        for (int off = 32; off; off >>= 1) ss += __shfl_down(ss, off);
        if ((threadIdx.x & 63) == 0) wsum[threadIdx.x >> 6] = ss;
        __syncthreads();
        float inv = 1.f / fmaxf(sqrtf(wsum[0] + wsum[1]), 1e-12f);
        __syncthreads();
        q[((b * Dd + d) * Tt + t) * NWIN + n] = acc[t] * inv;
    }
}

// ---------------------------------------------------------------------------
// K3: q_sp[b,d,t,s] = (sum_n q[b,d,t,n] * ws[b,t,s,n]) / (cnt[b,t,s]+1e-20)
// grid = 256, block = 256 -> one thread per output, coalesced store
__global__ void k_qsp(const float* __restrict__ q, const float* __restrict__ ws,
                      const float* __restrict__ cnt, float* __restrict__ qsp) {
    int tid = blockIdx.x * 256 + threadIdx.x;   // == ((b*D+d)*T+t)*SP+s
    int s = tid & 63;
    int t = (tid >> 6) & 3;
    int d = (tid >> 8) & 127;
    int b = tid >> 15;
    const float* qrow = q + ((b * Dd + d) * Tt + t) * NWIN;
    const float* wrow = ws + ((b * Tt + t) * SP + s) * NWIN;
    float acc = 0.f;
    #pragma unroll
    for (int n = 0; n < NWIN; ++n) acc += qrow[n] * wrow[n];
    qsp[tid] = acc / (cnt[(b * Tt + t) * SP + s] + 1e-20f);
}

// ---------------------------------------------------------------------------
// K4: As[b,t,n,m] = sum_d qsp[b,d,t,n]*qsp[b,d,t+1,m]; then
// A12 = zero_softmax(As/TEMP) rows, A21 = zero_softmax(As^T/TEMP) rows.
// grid = B*3 = 6, block = 256
__global__ void k_as(const float* __restrict__ qsp,
                     float* __restrict__ A12, float* __restrict__ A21) {
    int blk = blockIdx.x;
    int t = blk % 3, b = blk / 3;
    __shared__ float qa[32 * SP];
    __shared__ float qb[32 * SP];
    __shared__ float eb[SP * SP];
    __shared__ float rs[SP], cs[SP];

    float acc[16];
    #pragma unroll
    for (int j = 0; j < 16; ++j) acc[j] = 0.f;

    for (int d0 = 0; d0 < Dd; d0 += 32) {
        __syncthreads();
        for (int i = threadIdx.x; i < 32 * SP; i += 256) {
            int dd = i >> 6, s = i & 63;
            qa[i] = qsp[((b * Dd + d0 + dd) * Tt + t) * SP + s];
            qb[i] = qsp[((b * Dd + d0 + dd) * Tt + t + 1) * SP + s];
        }
        __syncthreads();
        #pragma unroll
        for (int j = 0; j < 16; ++j) {
            int e = j * 256 + threadIdx.x;
            int n = e >> 6, m = e & 63;
            float a = 0.f;
            for (int dd = 0; dd < 32; ++dd) a += qa[dd * 64 + n] * qb[dd * 64 + m];
            acc[j] += a;
        }
    }
    #pragma unroll
    for (int j = 0; j < 16; ++j) {
        int e = j * 256 + threadIdx.x;
        float x = acc[j] / 0.07f;
        float ex = expf(x) - 1.f;
        eb[e] = ex * ex;
    }
    __syncthreads();
    if (threadIdx.x < 64) {
        int n = threadIdx.x;
        float a = 0.f;
        for (int m = 0; m < 64; ++m) a += eb[n * 64 + m];
        rs[n] = a + 1e-5f;
    } else if (threadIdx.x < 128) {
        int m = threadIdx.x - 64;
        float a = 0.f;
        for (int n = 0; n < 64; ++n) a += eb[n * 64 + m];
        cs[m] = a + 1e-5f;
    }
    __syncthreads();
    float* a12 = A12 + (b * 3 + t) * SP * SP;
    float* a21 = A21 + (b * 3 + t) * SP * SP;
    for (int e = threadIdx.x; e < SP * SP; e += 256) {
        int n = e >> 6, m = e & 63;
        float v = eb[e];
        a12[e] = v / rs[n];
        a21[m * 64 + n] = v / cs[m];
    }
}

// ---------------------------------------------------------------------------
// K5: chain matmuls, all in LDS (64 KB). grid = B = 2, block = 256.
// aa1 = A12_0 @ A12_1 @ A21_1 @ A21_0
// aa2 = A12_0 @ A12_1 @ A12_2 @ A21_2 @ A21_1 @ A21_0
__device__ inline void mm64(float* dst, const float* A, const float* Bm) {
    #pragma unroll
    for (int j = 0; j < 16; ++j) {
        int e = j * 256 + threadIdx.x;
        int n = e >> 6, m = e & 63;
        float acc = 0.f;
        for (int k = 0; k < 64; ++k) acc += A[n * 64 + k] * Bm[k * 64 + m];
        dst[e] = acc;
    }
}

__global__ void k_chain(const float* __restrict__ A12, const float* __restrict__ A21,
                        float* __restrict__ out) {
    int b = blockIdx.x;
    __shared__ float X0[4096], X1[4096], X2[4096], X3[4096];
    const float* a12 = A12 + b * 3 * 4096;
    const float* a21 = A21 + b * 3 * 4096;

    for (int e = threadIdx.x; e < 4096; e += 256) { X0[e] = a12[e]; X1[e] = a12[4096 + e]; }
    __syncthreads();
    mm64(X2, X0, X1);                 // X2 = P = A12_0 @ A12_1
    __syncthreads();
    for (int e = threadIdx.x; e < 4096; e += 256) { X0[e] = a21[4096 + e]; X1[e] = a21[e]; }
    __syncthreads();
    mm64(X3, X2, X0);                 // X3 = P @ A21_1
    __syncthreads();
    mm64(X0, X3, X1);                 // X0 = aa1
    __syncthreads();
    float* aa1 = out + 1 + (0 * Bb + b) * 4096;
    for (int e = threadIdx.x; e < 4096; e += 256) aa1[e] = X0[e];
    for (int e = threadIdx.x; e < 4096; e += 256) X1[e] = a12[2 * 4096 + e];
    __syncthreads();
    mm64(X3, X2, X1);                 // X3 = P @ A12_2
    __syncthreads();
    for (int e = threadIdx.x; e < 4096; e += 256) X1[e] = a21[2 * 4096 + e];
    __syncthreads();
    mm64(X0, X3, X1);                 // X0 = P @ A12_2 @ A21_2
    __syncthreads();
    for (int e = threadIdx.x; e < 4096; e += 256) X1[e] = a21[4096 + e];
    __syncthreads();
    mm64(X3, X0, X1);                 // X3 = ... @ A21_1
    __syncthreads();
    for (int e = threadIdx.x; e < 4096; e += 256) X1[e] = a21[e];
    __syncthreads();
    mm64(X0, X3, X1);                 // X0 = aa2
    __syncthreads();
    float* aa2 = out + 1 + (1 * Bb + b) * 4096;
    for (int e = threadIdx.x; e < 4096; e += 256) aa2[e] = X0[e];
}

// ---------------------------------------------------------------------------
// K6: loss = sum_i mean_{b,n} [ log(sum_m(aa+EPS)) - log(aa[n,n]+EPS) ]
// 1 block, 256 threads (one per row: r = i*128 + b*64 + n)
__global__ void k_loss(float* __restrict__ out) {
    int r = threadIdx.x;
    const float* row = out + 1 + r * 64;
    float sum = 0.f;
    for (int m = 0; m < 64; ++m) sum += row[m] + 1e-20f;
    float diag = row[r & 63] + 1e-20f;
    float v = logf(sum) - logf(diag);
    for (int off = 32; off; off >>= 1) v += __shfl_down(v, off);
    __shared__ float acc[4];
    if ((threadIdx.x & 63) == 0) acc[threadIdx.x >> 6] = v;
    __syncthreads();
    if (threadIdx.x == 0) out[0] = (acc[0] + acc[1] + acc[2] + acc[3]) / 128.f;
}

// ---------------------------------------------------------------------------
extern "C" void kernel_launch(void* const* d_in, const int* in_sizes, int n_in,
                              void* d_out, int out_size, void* d_ws, size_t ws_size,
                              hipStream_t stream) {
    const float* feats = (const float*)d_in[0];
    const float* Wh    = (const float*)d_in[1];
    const int*   mask  = (const int*)d_in[2];
    float* out = (float*)d_out;
    float* ws  = (float*)d_ws;

    float* ws_sums = ws + OFF_WS;
    float* cnt     = ws + OFF_CNT;
    float* q       = ws + OFF_Q;
    float* qsp     = ws + OFF_QSP;
    float* A12     = ws + OFF_A12;
    float* A21     = ws + OFF_A21;

    hipMemsetAsync(d_ws, 0, (OFF_CNT + Bb * Tt * SP) * sizeof(float), stream);
    k_scatter<<<Bb * Tt * 8, 256, 0, stream>>>(mask, ws_sums, cnt);
    k_q<<<Bb * NWIN, 128, 0, stream>>>(feats, Wh, q);
    k_qsp<<<256, 256, 0, stream>>>(q, ws_sums, cnt, qsp);
    k_as<<<Bb * 3, 256, 0, stream>>>(qsp, A12, A21);
    k_chain<<<Bb, 256, 0, stream>>>(A12, A21, out);
    k_loss<<<1, 256, 0, stream>>>(out);
}

// Round 2
// 368.869 us; speedup vs baseline: 1.1171x; 1.1171x over previous
//
#include <hip/hip_runtime.h>
#include <hip/hip_bf16.h>

// Problem constants (fixed by reference setup_inputs)
constexpr int NWIN = 49;     // 7x7 windows
constexpr int LDP  = 68;     // padded LDS leading dim for 64-wide tiles

// workspace layout (float offsets)
constexpr int OFF_WS   = 0;        // [8][64][49]      = 25088  (bt, s, win)
constexpr int OFF_Q    = 25088;    // [2][128][4][49]  = 50176  (b, d, t, n)
constexpr int OFF_QSP  = 75264;    // [2][128][4][64]  = 65536  (b, d, t, s)
constexpr int OFF_A12  = 140800;   // [2][3][64][64]   = 24576
constexpr int OFF_A12T = 165376;   // [2][3][64][64]
constexpr int OFF_A21T = 189952;   // [2][3][64][64]   (end = 214528 floats)

// ---------------------------------------------------------------------------
// K1: per-(bt,window) label-weighted histogram.
// ws[bt,s,win] = sum over window pixels with label s of 1/sm(y,x).
// Note: sum_win ws[bt,s,win] == pixel count of label s (coverage * 1/sm = 1),
// so the denominator needs no separate counter.
// grid = 8*49 = 392, block = 256
__global__ void k_scatter(const int* __restrict__ mask, float* __restrict__ ws) {
    int win = blockIdx.x % NWIN;
    int bt  = blockIdx.x / NWIN;
    int wy = win / 7, wx = win % 7;
    __shared__ float loc[64];
    if (threadIdx.x < 64) loc[threadIdx.x] = 0.f;
    __syncthreads();
    const int* base = mask + bt * 65536 + (wy * 32) * 256 + wx * 32;
    #pragma unroll
    for (int it = 0; it < 16; ++it) {
        int idx = it * 256 + (int)threadIdx.x;
        int r = idx >> 6, c = idx & 63;
        int s = base[r * 256 + c];
        int y = wy * 32 + r, x = wx * 32 + c;
        float w = 1.f;
        if (y >= 32 && y < 224) w *= 0.5f;   // row coverage = 2
        if (x >= 32 && x < 224) w *= 0.5f;   // col coverage = 2
        atomicAdd(&loc[s], w);
    }
    __syncthreads();
    if (threadIdx.x < 64)
        ws[(bt * 64 + (int)threadIdx.x) * NWIN + win] = loc[threadIdx.x];
}

// ---------------------------------------------------------------------------
// K2: q[b,d,t,n] = normalize_d( sum_c feats[b,n,c,t] * W_head[c,d] )
// grid = 98, block = 256: thread = (d, c-half); unroll-8 ILP on global loads.
__global__ void k_q(const float* __restrict__ feats, const float* __restrict__ Wh,
                    float* __restrict__ q) {
    int n = blockIdx.x % NWIN, b = blockIdx.x / NWIN;
    __shared__ float4 f4[512];        // f[c][t] as float4 over t
    __shared__ float4 psum4[256];     // [ch][d]
    __shared__ float4 red4[2];
    const float4* fp4 = (const float4*)(feats + (size_t)(b * NWIN + n) * 2048);
    for (int i = threadIdx.x; i < 512; i += 256) f4[i] = fp4[i];
    __syncthreads();

    int d = threadIdx.x & 127, ch = threadIdx.x >> 7;
    float a0 = 0.f, a1 = 0.f, a2 = 0.f, a3 = 0.f;
    const float* wp = Wh + d;
    int c0 = ch * 256;
    #pragma unroll 8
    for (int c = c0; c < c0 + 256; ++c) {
        float w = wp[c * 128];
        float4 fv = f4[c];
        a0 += fv.x * w; a1 += fv.y * w; a2 += fv.z * w; a3 += fv.w * w;
    }
    psum4[threadIdx.x] = make_float4(a0, a1, a2, a3);
    __syncthreads();

    float4 A;
    if (threadIdx.x < 128) {
        float4 p0 = psum4[threadIdx.x], p1 = psum4[128 + threadIdx.x];
        A = make_float4(p0.x + p1.x, p0.y + p1.y, p0.z + p1.z, p0.w + p1.w);
        float sx = A.x * A.x, sy = A.y * A.y, sz = A.z * A.z, sw = A.w * A.w;
        for (int off = 32; off; off >>= 1) {
            sx += __shfl_down(sx, off); sy += __shfl_down(sy, off);
            sz += __shfl_down(sz, off); sw += __shfl_down(sw, off);
        }
        if ((threadIdx.x & 63) == 0) red4[threadIdx.x >> 6] = make_float4(sx, sy, sz, sw);
    }
    __syncthreads();
    if (threadIdx.x < 128) {
        float4 r0 = red4[0], r1 = red4[1];
        float ix = 1.f / fmaxf(sqrtf(r0.x + r1.x), 1e-12f);
        float iy = 1.f / fmaxf(sqrtf(r0.y + r1.y), 1e-12f);
        float iz = 1.f / fmaxf(sqrtf(r0.z + r1.z), 1e-12f);
        float iw = 1.f / fmaxf(sqrtf(r0.w + r1.w), 1e-12f);
        float* qb = q + ((size_t)(b * 128 + d) * 4) * NWIN + n;
        qb[0 * NWIN] = A.x * ix;
        qb[1 * NWIN] = A.y * iy;
        qb[2 * NWIN] = A.z * iz;
        qb[3 * NWIN] = A.w * iw;
    }
}

// ---------------------------------------------------------------------------
// K3: qsp[b,d,t,s] = (sum_n q[b,d,t,n]*ws[bt,s,n]) / (sum_n ws[bt,s,n] + 1e-20)
// grid = 256, block = 256 (one thread per output)
__global__ void k_qsp(const float* __restrict__ q, const float* __restrict__ ws,
                      float* __restrict__ qsp) {
    int tid = blockIdx.x * 256 + threadIdx.x;   // ((b*128+d)*4+t)*64+s
    int s = tid & 63;
    int t = (tid >> 6) & 3;
    int d = (tid >> 8) & 127;
    int b = tid >> 15;
    const float* qrow = q + ((b * 128 + d) * 4 + t) * NWIN;
    const float* wrow = ws + ((b * 4 + t) * 64 + s) * NWIN;
    float acc = 0.f, den = 0.f;
    #pragma unroll
    for (int n = 0; n < NWIN; ++n) {
        float w = wrow[n];
        den += w;
        acc += qrow[n] * w;
    }
    qsp[tid] = acc / (den + 1e-20f);
}

// ---------------------------------------------------------------------------
// K4: As[n,m] = sum_d qsp[b,d,t,n]*qsp[b,d,t+1,m]; zero_softmax both ways.
// Emits a12 (natural), a12T, a21T (transposed = natural order of eb/cs).
// Also zeroes out[0] for the fused loss accumulation in k_chain.
// grid = 6, block = 256. 4x4 strided register tiles, transposed LDS operands.
__global__ void k_as(const float* __restrict__ qsp,
                     float* __restrict__ a12, float* __restrict__ a12T,
                     float* __restrict__ a21T, float* __restrict__ out) {
    int t = blockIdx.x % 3, b = blockIdx.x / 3;
    if (blockIdx.x == 0 && threadIdx.x == 0) out[0] = 0.f;

    __shared__ float smem[2 * 64 * LDP];        // qaT|qbT, reused for eb|rs|cs
    float* qaT = smem;                           // [64 s][68 dd]
    float* qbT = smem + 64 * LDP;

    int nl = threadIdx.x >> 4, ml = threadIdx.x & 15;
    float acc[16];
    #pragma unroll
    for (int i = 0; i < 16; ++i) acc[i] = 0.f;

    for (int p = 0; p < 2; ++p) {
        __syncthreads();
        #pragma unroll
        for (int it = 0; it < 16; ++it) {
            int idx = it * 256 + (int)threadIdx.x;
            int dd = idx >> 6, s = idx & 63;
            qaT[s * LDP + dd] = qsp[((b * 128 + p * 64 + dd) * 4 + t) * 64 + s];
            qbT[s * LDP + dd] = qsp[((b * 128 + p * 64 + dd) * 4 + t + 1) * 64 + s];
        }
        __syncthreads();
        #pragma unroll
        for (int k0 = 0; k0 < 64; k0 += 4) {
            float4 av[4], bv[4];
            #pragma unroll
            for (int i = 0; i < 4; ++i) av[i] = *(const float4*)&qaT[(nl + 16 * i) * LDP + k0];
            #pragma unroll
            for (int j = 0; j < 4; ++j) bv[j] = *(const float4*)&qbT[(ml + 16 * j) * LDP + k0];
            #pragma unroll
            for (int i = 0; i < 4; ++i)
                #pragma unroll
                for (int j = 0; j < 4; ++j)
                    acc[i * 4 + j] += av[i].x * bv[j].x + av[i].y * bv[j].y
                                    + av[i].z * bv[j].z + av[i].w * bv[j].w;
        }
    }
    __syncthreads();

    float* eb = smem;                 // [64][65]
    float* rs = smem + 64 * 65;       // [64]
    float* cs = smem + 64 * 65 + 64;  // [64]
    #pragma unroll
    for (int i = 0; i < 4; ++i)
        #pragma unroll
        for (int j = 0; j < 4; ++j) {
            int n = nl + 16 * i, m = ml + 16 * j;
            float x = acc[i * 4 + j] * (1.f / 0.07f);
            float ex = expf(x) - 1.f;
            eb[n * 65 + m] = ex * ex;
        }
    __syncthreads();
    if (threadIdx.x < 128) {
        int r = threadIdx.x & 63;
        bool isrow = threadIdx.x < 64;
        float a = 0.f;
        #pragma unroll
        for (int k = 0; k < 64; ++k) a += isrow ? eb[r * 65 + k] : eb[k * 65 + r];
        (isrow ? rs : cs)[r] = a + 1e-5f;
    }
    __syncthreads();
    float* p12  = a12  + (b * 3 + t) * 4096;
    float* p12T = a12T + (b * 3 + t) * 4096;
    float* p21T = a21T + (b * 3 + t) * 4096;
    #pragma unroll
    for (int i = 0; i < 4; ++i)
        #pragma unroll
        for (int j = 0; j < 4; ++j) {
            int n = nl + 16 * i, m = ml + 16 * j;
            float v = eb[n * 65 + m];
            float v12 = v / rs[n];
            p12[n * 64 + m]  = v12;     // A12[n][m]
            p12T[m * 64 + n] = v12;     // A12^T rows (B-operand form)
            p21T[n * 64 + m] = v / cs[m]; // A21^T rows == eb/cs natural order
        }
}

// ---------------------------------------------------------------------------
// K5: chain matmuls. C[n,m] = dot(Ra[n,:], Rb[m,:]) with both operands
// row-contiguous-in-k in padded LDS (Ra = natural A, Rb = B^T).
__device__ __forceinline__ void ld_tile(float* dst, const float* __restrict__ src) {
    #pragma unroll
    for (int it = 0; it < 4; ++it) {
        int idx = it * 256 + (int)threadIdx.x;
        int r = idx >> 4, c4 = (idx & 15) * 4;
        *(float4*)&dst[r * LDP + c4] = *(const float4*)&src[r * 64 + c4];
    }
}

__device__ __forceinline__ void mm_dot(float* Cl, float* __restrict__ Cg,
                                       const float* Ra, const float* Rb) {
    int nl = threadIdx.x >> 4, ml = threadIdx.x & 15;
    float acc[16];
    #pragma unroll
    for (int i = 0; i < 16; ++i) acc[i] = 0.f;
    #pragma unroll
    for (int k0 = 0; k0 < 64; k0 += 4) {
        float4 av[4], bv[4];
        #pragma unroll
        for (int i = 0; i < 4; ++i) av[i] = *(const float4*)&Ra[(nl + 16 * i) * LDP + k0];
        #pragma unroll
        for (int j = 0; j < 4; ++j) bv[j] = *(const float4*)&Rb[(ml + 16 * j) * LDP + k0];
        #pragma unroll
        for (int i = 0; i < 4; ++i)
            #pragma unroll
            for (int j = 0; j < 4; ++j)
                acc[i * 4 + j] += av[i].x * bv[j].x + av[i].y * bv[j].y
                                + av[i].z * bv[j].z + av[i].w * bv[j].w;
    }
    #pragma unroll
    for (int i = 0; i < 4; ++i)
        #pragma unroll
        for (int j = 0; j < 4; ++j) {
            int n = nl + 16 * i, m = ml + 16 * j;
            if (Cl) Cl[n * LDP + m] = acc[i * 4 + j];
            if (Cg) Cg[n * 64 + m]  = acc[i * 4 + j];
        }
}

// grid = 4 (b, path), block = 256.
// path0: aa1 = (A12_0@A12_1)@A21_1@A21_0   (3 mm)
// path1: aa2 = (A12_0@A12_1)@A12_2@A21_2@A21_1@A21_0   (5 mm)
// Fused loss: per-block row-sums of its aa from LDS, atomicAdd into out[0].
__global__ void k_chain(const float* __restrict__ a12, const float* __restrict__ a12T,
                        const float* __restrict__ a21T, float* __restrict__ out) {
    int path = blockIdx.x & 1, b = blockIdx.x >> 1;
    __shared__ float X0[64 * LDP], X1[64 * LDP], X2[64 * LDP];
    const float* A12  = a12  + b * 3 * 4096;
    const float* A12T = a12T + b * 3 * 4096;
    const float* A21T = a21T + b * 3 * 4096;

    ld_tile(X0, A12);
    ld_tile(X1, A12T + 4096);
    __syncthreads();
    mm_dot(X2, nullptr, X0, X1);                 // P = A12_0 @ A12_1
    __syncthreads();

    float* aa_g;
    if (path == 0) {
        ld_tile(X1, A21T + 4096); __syncthreads();
        mm_dot(X0, nullptr, X2, X1); __syncthreads();      // T3 = P @ A21_1
        ld_tile(X1, A21T); __syncthreads();
        aa_g = out + 1 + (0 * 2 + b) * 4096;
        mm_dot(X2, aa_g, X0, X1);                          // aa1
    } else {
        ld_tile(X1, A12T + 2 * 4096); __syncthreads();
        mm_dot(X0, nullptr, X2, X1); __syncthreads();      // U = P @ A12_2
        ld_tile(X1, A21T + 2 * 4096); __syncthreads();
        mm_dot(X2, nullptr, X0, X1); __syncthreads();      // S = U @ A21_2
        ld_tile(X1, A21T + 4096); __syncthreads();
        mm_dot(X0, nullptr, X2, X1); __syncthreads();      // V = S @ A21_1
        ld_tile(X1, A21T); __syncthreads();
        aa_g = out + 1 + (2 + b) * 4096;
        mm_dot(X2, aa_g, X0, X1);                          // aa2
    }
    __syncthreads();
    // fused loss partial: mean over rows of [log(rowsum) - log(diag)] / 128
    if (threadIdx.x < 64) {
        int r = threadIdx.x;
        float sum = 0.f;
        #pragma unroll
        for (int m = 0; m < 64; ++m) sum += X2[r * LDP + m] + 1e-20f;
        float diag = X2[r * LDP + r] + 1e-20f;
        float v = logf(sum) - logf(diag);
        for (int off = 32; off; off >>= 1) v += __shfl_down(v, off);
        if (r == 0) atomicAdd(out, v * (1.f / 128.f));
    }
}

// ---------------------------------------------------------------------------
extern "C" void kernel_launch(void* const* d_in, const int* in_sizes, int n_in,
                              void* d_out, int out_size, void* d_ws, size_t ws_size,
                              hipStream_t stream) {
    const float* feats = (const float*)d_in[0];
    const float* Wh    = (const float*)d_in[1];
    const int*   mask  = (const int*)d_in[2];
    float* out = (float*)d_out;
    float* ws  = (float*)d_ws;

    float* ws_sums = ws + OFF_WS;
    float* q       = ws + OFF_Q;
    float* qsp     = ws + OFF_QSP;
    float* a12     = ws + OFF_A12;
    float* a12T    = ws + OFF_A12T;
    float* a21T    = ws + OFF_A21T;

    k_scatter<<<8 * NWIN, 256, 0, stream>>>(mask, ws_sums);
    k_q<<<2 * NWIN, 256, 0, stream>>>(feats, Wh, q);
    k_qsp<<<256, 256, 0, stream>>>(q, ws_sums, qsp);
    k_as<<<6, 256, 0, stream>>>(qsp, a12, a12T, a21T, out);
    k_chain<<<4, 256, 0, stream>>>(a12, a12T, a21T, out);
}

// Round 3
// 134.118 us; speedup vs baseline: 3.0723x; 2.7503x over previous
//
#include <hip/hip_runtime.h>
#include <hip/hip_bf16.h>

// Problem constants (fixed by reference setup_inputs)
constexpr int NWIN = 49;     // 7x7 windows
constexpr int LDP  = 68;     // padded LDS leading dim for 64-wide tiles

// workspace layout (float offsets)
constexpr int OFF_WS   = 0;        // [8][64][49]      = 25088  (bt, s, win)
constexpr int OFF_Q    = 25088;    // [2][128][4][49]  = 50176  (b, d, t, n)
constexpr int OFF_QSP  = 75264;    // [2][128][4][64]  = 65536  (b, d, t, s)
constexpr int OFF_A12  = 140800;   // [2][3][64][64]   = 24576
constexpr int OFF_A12T = 165376;   // [2][3][64][64]
constexpr int OFF_A21T = 189952;   // [2][3][64][64]   (end = 214528 floats)

// ---------------------------------------------------------------------------
// K1: per-(bt,window) label-weighted histogram.
// ws[bt,s,win] = sum over window pixels with label s of 1/sm(y,x).
// Note: sum_win ws[bt,s,win] == pixel count of label s (coverage * 1/sm = 1),
// so the denominator needs no separate counter.
// grid = 8*49 = 392, block = 256
__global__ void k_scatter(const int* __restrict__ mask, float* __restrict__ ws) {
    int win = blockIdx.x % NWIN;
    int bt  = blockIdx.x / NWIN;
    int wy = win / 7, wx = win % 7;
    __shared__ float loc[64];
    if (threadIdx.x < 64) loc[threadIdx.x] = 0.f;
    __syncthreads();
    const int* base = mask + bt * 65536 + (wy * 32) * 256 + wx * 32;
    #pragma unroll
    for (int it = 0; it < 16; ++it) {
        int idx = it * 256 + (int)threadIdx.x;
        int r = idx >> 6, c = idx & 63;
        int s = base[r * 256 + c];
        int y = wy * 32 + r, x = wx * 32 + c;
        float w = 1.f;
        if (y >= 32 && y < 224) w *= 0.5f;   // row coverage = 2
        if (x >= 32 && x < 224) w *= 0.5f;   // col coverage = 2
        atomicAdd(&loc[s], w);
    }
    __syncthreads();
    if (threadIdx.x < 64)
        ws[(bt * 64 + (int)threadIdx.x) * NWIN + win] = loc[threadIdx.x];
}

// ---------------------------------------------------------------------------
// K2: q[b,d,t,n] = normalize_d( sum_c feats[b,n,c,t] * W_head[c,d] )
// grid = 98, block = 256: thread = (d, c-half); unroll-8 ILP on global loads.
__global__ void __launch_bounds__(256, 1)
k_q(const float* __restrict__ feats, const float* __restrict__ Wh,
    float* __restrict__ q) {
    int n = blockIdx.x % NWIN, b = blockIdx.x / NWIN;
    __shared__ float4 f4[512];        // f[c][t] as float4 over t
    __shared__ float4 psum4[256];     // [ch][d]
    __shared__ float4 red4[2];
    const float4* fp4 = (const float4*)(feats + (size_t)(b * NWIN + n) * 2048);
    for (int i = threadIdx.x; i < 512; i += 256) f4[i] = fp4[i];
    __syncthreads();

    int d = threadIdx.x & 127, ch = threadIdx.x >> 7;
    float a0 = 0.f, a1 = 0.f, a2 = 0.f, a3 = 0.f;
    const float* wp = Wh + d;
    int c0 = ch * 256;
    #pragma unroll 8
    for (int c = c0; c < c0 + 256; ++c) {
        float w = wp[c * 128];
        float4 fv = f4[c];
        a0 += fv.x * w; a1 += fv.y * w; a2 += fv.z * w; a3 += fv.w * w;
    }
    psum4[threadIdx.x] = make_float4(a0, a1, a2, a3);
    __syncthreads();

    float4 A;
    if (threadIdx.x < 128) {
        float4 p0 = psum4[threadIdx.x], p1 = psum4[128 + threadIdx.x];
        A = make_float4(p0.x + p1.x, p0.y + p1.y, p0.z + p1.z, p0.w + p1.w);
        float sx = A.x * A.x, sy = A.y * A.y, sz = A.z * A.z, sw = A.w * A.w;
        for (int off = 32; off; off >>= 1) {
            sx += __shfl_down(sx, off); sy += __shfl_down(sy, off);
            sz += __shfl_down(sz, off); sw += __shfl_down(sw, off);
        }
        if ((threadIdx.x & 63) == 0) red4[threadIdx.x >> 6] = make_float4(sx, sy, sz, sw);
    }
    __syncthreads();
    if (threadIdx.x < 128) {
        float4 r0 = red4[0], r1 = red4[1];
        float ix = 1.f / fmaxf(sqrtf(r0.x + r1.x), 1e-12f);
        float iy = 1.f / fmaxf(sqrtf(r0.y + r1.y), 1e-12f);
        float iz = 1.f / fmaxf(sqrtf(r0.z + r1.z), 1e-12f);
        float iw = 1.f / fmaxf(sqrtf(r0.w + r1.w), 1e-12f);
        float* qb = q + ((size_t)(b * 128 + d) * 4) * NWIN + n;
        qb[0 * NWIN] = A.x * ix;
        qb[1 * NWIN] = A.y * iy;
        qb[2 * NWIN] = A.z * iz;
        qb[3 * NWIN] = A.w * iw;
    }
}

// ---------------------------------------------------------------------------
// K3: qsp[b,d,t,s] = (sum_n q[b,d,t,n]*ws[bt,s,n]) / (sum_n ws[bt,s,n] + 1e-20)
// grid = 256, block = 256 (one thread per output)
__global__ void k_qsp(const float* __restrict__ q, const float* __restrict__ ws,
                      float* __restrict__ qsp) {
    int tid = blockIdx.x * 256 + threadIdx.x;   // ((b*128+d)*4+t)*64+s
    int s = tid & 63;
    int t = (tid >> 6) & 3;
    int d = (tid >> 8) & 127;
    int b = tid >> 15;
    const float* qrow = q + ((b * 128 + d) * 4 + t) * NWIN;
    const float* wrow = ws + ((b * 4 + t) * 64 + s) * NWIN;
    float acc = 0.f, den = 0.f;
    #pragma unroll
    for (int n = 0; n < NWIN; ++n) {
        float w = wrow[n];
        den += w;
        acc += qrow[n] * w;
    }
    qsp[tid] = acc / (den + 1e-20f);
}

// ---------------------------------------------------------------------------
// K4: As[n,m] = sum_d qsp[b,d,t,n]*qsp[b,d,t+1,m]; zero_softmax both ways.
// Emits a12 (natural), a12T, a21T (transposed = natural order of eb/cs).
// Also zeroes out[0] for the fused loss accumulation in k_chain.
// grid = 6, block = 256. 4x4 strided register tiles, transposed LDS operands.
// __launch_bounds__(256,1): the 48-float register tile MUST stay in VGPRs —
// without it the allocator caps at 64 VGPRs and spills the tile to scratch.
__global__ void __launch_bounds__(256, 1)
k_as(const float* __restrict__ qsp,
     float* __restrict__ a12, float* __restrict__ a12T,
     float* __restrict__ a21T, float* __restrict__ out) {
    int t = blockIdx.x % 3, b = blockIdx.x / 3;
    if (blockIdx.x == 0 && threadIdx.x == 0) out[0] = 0.f;

    __shared__ float smem[2 * 64 * LDP];        // qaT|qbT, reused for eb|rs|cs
    float* qaT = smem;                           // [64 s][68 dd]
    float* qbT = smem + 64 * LDP;

    int nl = threadIdx.x >> 4, ml = threadIdx.x & 15;
    float acc[16];
    #pragma unroll
    for (int i = 0; i < 16; ++i) acc[i] = 0.f;

    for (int p = 0; p < 2; ++p) {
        __syncthreads();
        #pragma unroll
        for (int it = 0; it < 16; ++it) {
            int idx = it * 256 + (int)threadIdx.x;
            int dd = idx >> 6, s = idx & 63;
            qaT[s * LDP + dd] = qsp[((b * 128 + p * 64 + dd) * 4 + t) * 64 + s];
            qbT[s * LDP + dd] = qsp[((b * 128 + p * 64 + dd) * 4 + t + 1) * 64 + s];
        }
        __syncthreads();
        #pragma unroll
        for (int k0 = 0; k0 < 64; k0 += 4) {
            float4 av[4], bv[4];
            #pragma unroll
            for (int i = 0; i < 4; ++i) av[i] = *(const float4*)&qaT[(nl + 16 * i) * LDP + k0];
            #pragma unroll
            for (int j = 0; j < 4; ++j) bv[j] = *(const float4*)&qbT[(ml + 16 * j) * LDP + k0];
            #pragma unroll
            for (int i = 0; i < 4; ++i)
                #pragma unroll
                for (int j = 0; j < 4; ++j)
                    acc[i * 4 + j] += av[i].x * bv[j].x + av[i].y * bv[j].y
                                    + av[i].z * bv[j].z + av[i].w * bv[j].w;
        }
    }
    __syncthreads();

    float* eb = smem;                 // [64][65]
    float* rs = smem + 64 * 65;       // [64]
    float* cs = smem + 64 * 65 + 64;  // [64]
    #pragma unroll
    for (int i = 0; i < 4; ++i)
        #pragma unroll
        for (int j = 0; j < 4; ++j) {
            int n = nl + 16 * i, m = ml + 16 * j;
            float x = acc[i * 4 + j] * (1.f / 0.07f);
            float ex = expf(x) - 1.f;
            eb[n * 65 + m] = ex * ex;
        }
    __syncthreads();
    if (threadIdx.x < 128) {
        int r = threadIdx.x & 63;
        bool isrow = threadIdx.x < 64;
        float a = 0.f;
        #pragma unroll
        for (int k = 0; k < 64; ++k) a += isrow ? eb[r * 65 + k] : eb[k * 65 + r];
        (isrow ? rs : cs)[r] = a + 1e-5f;
    }
    __syncthreads();
    float* p12  = a12  + (b * 3 + t) * 4096;
    float* p12T = a12T + (b * 3 + t) * 4096;
    float* p21T = a21T + (b * 3 + t) * 4096;
    #pragma unroll
    for (int i = 0; i < 4; ++i)
        #pragma unroll
        for (int j = 0; j < 4; ++j) {
            int n = nl + 16 * i, m = ml + 16 * j;
            float v = eb[n * 65 + m];
            float v12 = v / rs[n];
            p12[n * 64 + m]  = v12;     // A12[n][m]
            p12T[m * 64 + n] = v12;     // A12^T rows (B-operand form)
            p21T[n * 64 + m] = v / cs[m]; // A21^T rows == eb/cs natural order
        }
}

// ---------------------------------------------------------------------------
// K5: chain matmuls. C[n,m] = dot(Ra[n,:], Rb[m,:]) with both operands
// row-contiguous-in-k in padded LDS (Ra = natural A, Rb = B^T).
__device__ __forceinline__ void ld_tile(float* dst, const float* __restrict__ src) {
    #pragma unroll
    for (int it = 0; it < 4; ++it) {
        int idx = it * 256 + (int)threadIdx.x;
        int r = idx >> 4, c4 = (idx & 15) * 4;
        *(float4*)&dst[r * LDP + c4] = *(const float4*)&src[r * 64 + c4];
    }
}

template <bool TO_LDS, bool TO_GLB>
__device__ __forceinline__ void mm_dot(float* Cl, float* __restrict__ Cg,
                                       const float* Ra, const float* Rb) {
    int nl = threadIdx.x >> 4, ml = threadIdx.x & 15;
    float acc[16];
    #pragma unroll
    for (int i = 0; i < 16; ++i) acc[i] = 0.f;
    #pragma unroll
    for (int k0 = 0; k0 < 64; k0 += 4) {
        float4 av[4], bv[4];
        #pragma unroll
        for (int i = 0; i < 4; ++i) av[i] = *(const float4*)&Ra[(nl + 16 * i) * LDP + k0];
        #pragma unroll
        for (int j = 0; j < 4; ++j) bv[j] = *(const float4*)&Rb[(ml + 16 * j) * LDP + k0];
        #pragma unroll
        for (int i = 0; i < 4; ++i)
            #pragma unroll
            for (int j = 0; j < 4; ++j)
                acc[i * 4 + j] += av[i].x * bv[j].x + av[i].y * bv[j].y
                                + av[i].z * bv[j].z + av[i].w * bv[j].w;
    }
    #pragma unroll
    for (int i = 0; i < 4; ++i)
        #pragma unroll
        for (int j = 0; j < 4; ++j) {
            int n = nl + 16 * i, m = ml + 16 * j;
            if (TO_LDS) Cl[n * LDP + m] = acc[i * 4 + j];
            if (TO_GLB) Cg[n * 64 + m]  = acc[i * 4 + j];
        }
}

// grid = 4 (b, path), block = 256.
// path0: aa1 = (A12_0@A12_1)@A21_1@A21_0   (3 mm)
// path1: aa2 = (A12_0@A12_1)@A12_2@A21_2@A21_1@A21_0   (5 mm)
// Fused loss: per-block row-sums of its aa from LDS, atomicAdd into out[0].
__global__ void __launch_bounds__(256, 1)
k_chain(const float* __restrict__ a12, const float* __restrict__ a12T,
        const float* __restrict__ a21T, float* __restrict__ out) {
    int path = blockIdx.x & 1, b = blockIdx.x >> 1;
    __shared__ float X0[64 * LDP], X1[64 * LDP], X2[64 * LDP];
    const float* A12  = a12  + b * 3 * 4096;
    const float* A12T = a12T + b * 3 * 4096;
    const float* A21T = a21T + b * 3 * 4096;

    ld_tile(X0, A12);
    ld_tile(X1, A12T + 4096);
    __syncthreads();
    mm_dot<true, false>(X2, nullptr, X0, X1);          // P = A12_0 @ A12_1
    __syncthreads();

    float* aa_g;
    if (path == 0) {
        ld_tile(X1, A21T + 4096); __syncthreads();
        mm_dot<true, false>(X0, nullptr, X2, X1); __syncthreads();  // P @ A21_1
        ld_tile(X1, A21T); __syncthreads();
        aa_g = out + 1 + (0 * 2 + b) * 4096;
        mm_dot<true, true>(X2, aa_g, X0, X1);                       // aa1
    } else {
        ld_tile(X1, A12T + 2 * 4096); __syncthreads();
        mm_dot<true, false>(X0, nullptr, X2, X1); __syncthreads();  // U = P @ A12_2
        ld_tile(X1, A21T + 2 * 4096); __syncthreads();
        mm_dot<true, false>(X2, nullptr, X0, X1); __syncthreads();  // S = U @ A21_2
        ld_tile(X1, A21T + 4096); __syncthreads();
        mm_dot<true, false>(X0, nullptr, X2, X1); __syncthreads();  // V = S @ A21_1
        ld_tile(X1, A21T); __syncthreads();
        aa_g = out + 1 + (2 + b) * 4096;
        mm_dot<true, true>(X2, aa_g, X0, X1);                       // aa2
    }
    __syncthreads();
    // fused loss partial: mean over rows of [log(rowsum) - log(diag)] / 128
    if (threadIdx.x < 64) {
        int r = threadIdx.x;
        float sum = 0.f;
        #pragma unroll
        for (int m = 0; m < 64; ++m) sum += X2[r * LDP + m] + 1e-20f;
        float diag = X2[r * LDP + r] + 1e-20f;
        float v = logf(sum) - logf(diag);
        for (int off = 32; off; off >>= 1) v += __shfl_down(v, off);
        if (r == 0) atomicAdd(out, v * (1.f / 128.f));
    }
}

// ---------------------------------------------------------------------------
extern "C" void kernel_launch(void* const* d_in, const int* in_sizes, int n_in,
                              void* d_out, int out_size, void* d_ws, size_t ws_size,
                              hipStream_t stream) {
    const float* feats = (const float*)d_in[0];
    const float* Wh    = (const float*)d_in[1];
    const int*   mask  = (const int*)d_in[2];
    float* out = (float*)d_out;
    float* ws  = (float*)d_ws;

    float* ws_sums = ws + OFF_WS;
    float* q       = ws + OFF_Q;
    float* qsp     = ws + OFF_QSP;
    float* a12     = ws + OFF_A12;
    float* a12T    = ws + OFF_A12T;
    float* a21T    = ws + OFF_A21T;

    k_scatter<<<8 * NWIN, 256, 0, stream>>>(mask, ws_sums);
    k_q<<<2 * NWIN, 256, 0, stream>>>(feats, Wh, q);
    k_qsp<<<256, 256, 0, stream>>>(q, ws_sums, qsp);
    k_as<<<6, 256, 0, stream>>>(qsp, a12, a12T, a21T, out);
    k_chain<<<4, 256, 0, stream>>>(a12, a12T, a21T, out);
}